// Round 7
// baseline (585.538 us; speedup 1.0000x reference)
//
#include <hip/hip_runtime.h>
#include <cstdint>
#include <cstddef>

// Causal self-attention. fp32 in / fp32 out. bf16 MFMA compute, fp32 accum.
// B=4 T=1024 C=2048 H=16 Dh=128.
//
// R7: attention rewritten barrier-free:
//  - S^T = K.Q^T formulation (operand swap; q lands on lane `col`) ->
//    softmax state m/l/alpha are per-lane scalars, shuffle reductions are
//    2 stages (xor 16,32) instead of 4.
//  - K/V fragments loaded DIRECT from global per wave (each wave consumed the
//    whole tile anyway; L2 eats the 4x redundancy) -> no staging LDS, no
//    __syncthreads in the k-loop. Only wave-private Ps (P C->A round-trip,
//    barrier-free, verified R4-R6) stays in LDS: 8.7 KB/block.
// GEMM path unchanged from R6 (clean attribution).

typedef __attribute__((ext_vector_type(8))) __bf16 bf16x8;
typedef __attribute__((ext_vector_type(4))) float f32x4;
typedef unsigned short u16;

#define NEG_BIG (-1.0e30f)

__device__ __forceinline__ u16 f2bf(float f) {
    union { float f; uint32_t u; } v; v.f = f;
    uint32_t r = v.u + 0x7FFFu + ((v.u >> 16) & 1u);   // RNE
    return (u16)(r >> 16);
}

__device__ __forceinline__ uint32_t pack2(float a, float b) {
    return (uint32_t)f2bf(a) | ((uint32_t)f2bf(b) << 16);
}

__device__ __forceinline__ f32x4 mfma16(bf16x8 a, bf16x8 b, f32x4 c) {
    return __builtin_amdgcn_mfma_f32_16x16x32_bf16(a, b, c, 0, 0, 0);
}

// async global->LDS, 16B/lane; LDS dst = wave-uniform base + lane*16
__device__ __forceinline__ void async16(const u16* g, u16* l) {
    __builtin_amdgcn_global_load_lds(
        (const __attribute__((address_space(1))) void*)g,
        (__attribute__((address_space(3))) void*)l, 16, 0, 0);
}

// ---------------------------------------------------------------------------
// x fp32 -> bf16, 8 elems/thread
// ---------------------------------------------------------------------------
__global__ __launch_bounds__(256) void cvt_bf16(
    const float* __restrict__ x, u16* __restrict__ xb) {
    size_t i = ((size_t)blockIdx.x * 256 + threadIdx.x) * 8;
    float4 u = *(const float4*)(x + i);
    float4 v = *(const float4*)(x + i + 4);
    uint4 p;
    p.x = pack2(u.x, u.y); p.y = pack2(u.z, u.w);
    p.z = pack2(v.x, v.y); p.w = pack2(v.z, v.w);
    *(uint4*)(xb + i) = p;
}

// ---------------------------------------------------------------------------
// Transpose+convert: W fp32 [2048 x ldW] -> WT bf16 [ncols][2048].
// ---------------------------------------------------------------------------
__global__ __launch_bounds__(256) void transpose_w(
    const float* __restrict__ W, int ldW, u16* __restrict__ WT) {
    __shared__ u16 tile[64][68];
    const int n0 = blockIdx.x * 64, k0 = blockIdx.y * 64;
    const int t = threadIdx.x;
    for (int i = t; i < 4096; i += 256) {
        int r = i >> 6, c = i & 63;
        tile[r][c] = f2bf(W[(size_t)(k0 + r) * ldW + n0 + c]);
    }
    __syncthreads();
    for (int i = t; i < 4096; i += 256) {
        int r = i >> 6, c = i & 63;          // r: n, c: k
        WT[(size_t)(n0 + r) * 2048 + k0 + c] = tile[c][r];
    }
}

// ---------------------------------------------------------------------------
// GEMM: C[M,N] = A[M,2048] @ Bt[N,2048]. 128x128 tile, BK=32, 4 waves.
// amode 0: A fp32 flat (VGPR pack)   amode 1: A bf16 BHTD gather (async16)
// amode 2: A bf16 flat (async16)     amode 3: A bf16 BHTD gather (VGPR)
// omode 0: fp32 outf[M][N]  omode 1: bf16 Qo[BHTD]  omode 2: bf16 Vt[BHDT]
// omode 3: merged-qkv scatter
// ---------------------------------------------------------------------------
__global__ __launch_bounds__(256) void gemm_k(
    const void* __restrict__ Av, const u16* __restrict__ Bt,
    int N, int amode, int omode,
    float* __restrict__ outf, u16* __restrict__ Qo, u16* __restrict__ Ko,
    u16* __restrict__ Vt) {
    const int K = 2048;
    __shared__ u16 As[128][32];
    __shared__ u16 Bs[128][32];

    const float* A32 = (const float*)Av;
    const u16*   A16 = (const u16*)Av;

    const int m0 = blockIdx.y * 128, n0 = blockIdx.x * 128;
    const int t = threadIdx.x;
    const int w = t >> 6, lane = t & 63;
    const int col = lane & 15, quad = lane >> 4;
    const int wrow = (w >> 1) * 64, wcol = (w & 1) * 64;

    f32x4 acc[4][4];
    #pragma unroll
    for (int i = 0; i < 4; ++i)
        #pragma unroll
        for (int j = 0; j < 4; ++j)
            acc[i][j] = (f32x4){0.f, 0.f, 0.f, 0.f};

    u16* as_flat = &As[0][0];
    u16* bs_flat = &Bs[0][0];
    const int c1 = (w << 6) | lane;
    const int c2 = c1 + 256;

    for (int k0 = 0; k0 < K; k0 += 32) {
        {
            const u16* g1 = Bt + (size_t)(n0 + (c1 >> 2)) * K + k0 + ((c1 & 3) << 3);
            async16(g1, bs_flat + (size_t)w * 512);
            const u16* g2 = Bt + (size_t)(n0 + (c2 >> 2)) * K + k0 + ((c2 & 3) << 3);
            async16(g2, bs_flat + 2048 + (size_t)w * 512);
        }
        if (amode == 2) {
            const u16* g1 = A16 + (size_t)(m0 + (c1 >> 2)) * K + k0 + ((c1 & 3) << 3);
            async16(g1, as_flat + (size_t)w * 512);
            const u16* g2 = A16 + (size_t)(m0 + (c2 >> 2)) * K + k0 + ((c2 & 3) << 3);
            async16(g2, as_flat + 2048 + (size_t)w * 512);
        } else if (amode == 1) {
            #pragma unroll
            for (int cc = 0; cc < 2; ++cc) {
                int c = cc ? c2 : c1;
                int r = c >> 2, ko = (c & 3) << 3;
                int kg = k0 + ko, h = kg >> 7, d = kg & 127;
                int m = m0 + r, b = m >> 10, tt = m & 1023;
                const u16* g = A16 + (((size_t)(b * 16 + h)) * 1024 + tt) * 128 + d;
                async16(g, as_flat + (size_t)(cc ? 2048 : 0) + (size_t)w * 512);
            }
        } else if (amode == 0) {
            #pragma unroll
            for (int c = t; c < 512; c += 256) {
                int r = c >> 2, ko = (c & 3) * 8;
                size_t off = (size_t)(m0 + r) * K + k0 + ko;
                float4 u = *(const float4*)(A32 + off);
                float4 v = *(const float4*)(A32 + off + 4);
                uint4 p;
                p.x = pack2(u.x, u.y); p.y = pack2(u.z, u.w);
                p.z = pack2(v.x, v.y); p.w = pack2(v.z, v.w);
                *(uint4*)&As[r][ko] = p;
            }
        } else {
            #pragma unroll
            for (int c = t; c < 512; c += 256) {
                int r = c >> 2, ko = (c & 3) * 8;
                int kg = k0 + ko, h = kg >> 7, d = kg & 127;
                int m = m0 + r, b = m >> 10, tt = m & 1023;
                *(uint4*)&As[r][ko] =
                    *(const uint4*)(A16 + (((size_t)(b * 16 + h)) * 1024 + tt) * 128 + d);
            }
        }
        __syncthreads();

        bf16x8 afr[4], bfr[4];
        #pragma unroll
        for (int i = 0; i < 4; ++i)
            afr[i] = *(const bf16x8*)&As[wrow + i * 16 + col][quad * 8];
        #pragma unroll
        for (int i = 0; i < 4; ++i)
            bfr[i] = *(const bf16x8*)&Bs[wcol + i * 16 + col][quad * 8];

        #pragma unroll
        for (int mt = 0; mt < 4; ++mt)
            #pragma unroll
            for (int nt = 0; nt < 4; ++nt)
                acc[mt][nt] = mfma16(afr[mt], bfr[nt], acc[mt][nt]);
        __syncthreads();
    }

    #pragma unroll
    for (int mt = 0; mt < 4; ++mt) {
        #pragma unroll
        for (int nt = 0; nt < 4; ++nt) {
            #pragma unroll
            for (int r = 0; r < 4; ++r) {
                int gm = m0 + wrow + mt * 16 + quad * 4 + r;
                int gn = n0 + wcol + nt * 16 + col;
                if (omode == 0) {
                    outf[(size_t)gm * N + gn] = acc[mt][nt][r];
                } else {
                    u16 bv = f2bf(acc[mt][nt][r]);
                    int b = gm >> 10, tq = gm & 1023;
                    if (omode == 3) {
                        int which = gn >> 11, rem = gn & 2047;
                        int h = rem >> 7, d = rem & 127;
                        size_t bh = (size_t)b * 16 + h;
                        if (which == 0)      Qo[(bh * 1024 + tq) * 128 + d] = bv;
                        else if (which == 1) Ko[(bh * 1024 + tq) * 128 + d] = bv;
                        else                 Vt[(bh * 128 + d) * 1024 + tq] = bv;
                    } else {
                        int h = gn >> 7, d = gn & 127;
                        size_t bh = (size_t)b * 16 + h;
                        if (omode == 1) Qo[(bh * 1024 + tq) * 128 + d] = bv;
                        else            Vt[(bh * 128 + d) * 1024 + tq] = bv;
                    }
                }
            }
        }
    }
}

// ---------------------------------------------------------------------------
// Flash attention, barrier-free S^T formulation.
// Grid (T/64, H, B), 256 threads = 4 independent waves; wave owns 16 q-rows.
// S^T = K.Q^T : lane holds S^T[t=tt*16+quad*4+r][q=col] -> softmax over t is
// a per-lane partial + 2-stage cross-quad shuffle; m/l/alpha are scalars.
// K,V fragments read directly from global (no staging LDS, no barriers).
// P round-trips through wave-private Ps[w] ([q][t], t contig) -> B-operand
// of O^T = V^T.P^T. O overwrites Q in place.
// ---------------------------------------------------------------------------
__global__ __launch_bounds__(256) void attn_kernel(
    u16* __restrict__ Q, const u16* __restrict__ K,
    const u16* __restrict__ VT) {
    __shared__ u16 Ps[4][16][68];   // [wave][q][t-padded], stride 68: 2-way free

    const int qb = (int)(gridDim.x - 1) - (int)blockIdx.x;   // heavy first
    const int h = blockIdx.y, b = blockIdx.z;
    const int t = threadIdx.x;
    const int w = t >> 6, lane = t & 63;
    const int col = lane & 15, quad = lane >> 4;
    const size_t bh = (size_t)b * 16 + h;
    u16* Qb = Q + bh * (1024 * 128);
    const u16* Kb = K + bh * (1024 * 128);
    const u16* Vb = VT + bh * (128 * 1024);
    const int q_lane = qb * 64 + w * 16 + col;   // this lane's q column

    // Q fragment, B-operand layout: lane holds Q[q=col][dh=kq*32+quad*8+j]
    bf16x8 qf[4];
    {
        const u16* qp = Qb + (size_t)q_lane * 128 + quad * 8;
        #pragma unroll
        for (int kq = 0; kq < 4; ++kq)
            qf[kq] = *(const bf16x8*)(qp + kq * 32);
    }

    f32x4 o[8];
    #pragma unroll
    for (int i = 0; i < 8; ++i) o[i] = (f32x4){0.f, 0.f, 0.f, 0.f};
    float m = NEG_BIG, l = 0.f;
    const float scale = 0.08838834764831845f;  // 1/sqrt(128)

    for (int kt = 0; kt <= qb; ++kt) {
        const u16* Kt = Kb + (size_t)kt * 64 * 128;

        // S^T = K.Q^T : A-frag = K[t=tt*16+col][dh], direct global
        f32x4 s[4];
        #pragma unroll
        for (int tt = 0; tt < 4; ++tt) {
            const u16* kp = Kt + (size_t)(tt * 16 + col) * 128 + quad * 8;
            f32x4 a = (f32x4){0.f, 0.f, 0.f, 0.f};
            #pragma unroll
            for (int kq = 0; kq < 4; ++kq)
                a = mfma16(*(const bf16x8*)(kp + kq * 32), qf[kq], a);
            s[tt] = a;
        }

        // scale + causal mask (t > q) + local max over 16 t-values
        const bool need_mask = (kt == qb);
        float rmax = NEG_BIG;
        #pragma unroll
        for (int tt = 0; tt < 4; ++tt) {
            #pragma unroll
            for (int r = 0; r < 4; ++r) {
                float v = s[tt][r] * scale;
                int tg = kt * 64 + tt * 16 + quad * 4 + r;
                if (need_mask && tg > q_lane) v = NEG_BIG;
                s[tt][r] = v;
                rmax = fmaxf(rmax, v);
            }
        }
        rmax = fmaxf(rmax, __shfl_xor(rmax, 16, 64));
        rmax = fmaxf(rmax, __shfl_xor(rmax, 32, 64));

        float mnew = fmaxf(m, rmax);
        float alpha = __expf(m - mnew);
        m = mnew;

        // P = exp(S^T - m); write into Ps[w][q=col][t] as packed u32 pairs
        float rsum = 0.f;
        #pragma unroll
        for (int tt = 0; tt < 4; ++tt) {
            float p0 = __expf(s[tt][0] - mnew);
            float p1 = __expf(s[tt][1] - mnew);
            float p2 = __expf(s[tt][2] - mnew);
            float p3 = __expf(s[tt][3] - mnew);
            rsum += (p0 + p1) + (p2 + p3);
            uint32_t* dst = (uint32_t*)&Ps[w][col][tt * 16 + quad * 4];
            dst[0] = pack2(p0, p1);
            dst[1] = pack2(p2, p3);
        }
        rsum += __shfl_xor(rsum, 16, 64);
        rsum += __shfl_xor(rsum, 32, 64);
        l = l * alpha + rsum;

        #pragma unroll
        for (int dt = 0; dt < 8; ++dt)
            #pragma unroll
            for (int r = 0; r < 4; ++r) o[dt][r] *= alpha;

        // O^T += V^T.P^T : A-frag = V^T[d=dt*16+col][t], direct global;
        // B-frag = Ps[w][col][ks*32+quad*8..] (t contiguous)
        #pragma unroll
        for (int ks = 0; ks < 2; ++ks) {
            bf16x8 pf = *(const bf16x8*)&Ps[w][col][ks * 32 + quad * 8];
            #pragma unroll
            for (int dt = 0; dt < 8; ++dt) {
                const u16* vp = Vb + (size_t)(dt * 16 + col) * 1024
                              + kt * 64 + ks * 32 + quad * 8;
                o[dt] = mfma16(*(const bf16x8*)vp, pf, o[dt]);
            }
        }
    }

    // epilogue: O^T lane holds (d = dt*16+quad*4+r, q = col); store O[q][d]
    float inv = 1.0f / l;
    #pragma unroll
    for (int dt = 0; dt < 8; ++dt) {
        #pragma unroll
        for (int r = 0; r < 4; ++r) {
            Qb[(size_t)q_lane * 128 + dt * 16 + quad * 4 + r] =
                f2bf(o[dt][r] * inv);
        }
    }
}

// ---------------------------------------------------------------------------
extern "C" void kernel_launch(void* const* d_in, const int* in_sizes, int n_in,
                              void* d_out, int out_size, void* d_ws, size_t ws_size,
                              hipStream_t stream) {
    const float* x      = (const float*)d_in[0];   // [4096, 2048]
    const float* w_qkv  = (const float*)d_in[1];   // [2048, 6144]
    const float* w_proj = (const float*)d_in[2];   // [2048, 2048]
    float* out = (float*)d_out;                    // [4096, 2048]

    const size_t SEG = (size_t)4 * 16 * 1024 * 128;      // 8,388,608 elems
    const size_t NEED_FAST = ((size_t)6144 * 2048 + SEG * 4) * 2;  // 92.3 MB

    if (ws_size >= NEED_FAST + (1u << 20)) {
        u16* wT = (u16*)d_ws;                 // 6144*2048, reused for proj
        u16* xb = wT + (size_t)6144 * 2048;
        u16* Qb = xb + SEG;
        u16* Kb = Qb + SEG;
        u16* Vb = Kb + SEG;

        cvt_bf16<<<4096, 256, 0, stream>>>(x, xb);
        transpose_w<<<dim3(96, 32), 256, 0, stream>>>(w_qkv, 6144, wT);

        gemm_k<<<dim3(48, 32), 256, 0, stream>>>(xb, wT, 6144, 2, 3,
                                                 nullptr, Qb, Kb, Vb);

        attn_kernel<<<dim3(16, 16, 4), 256, 0, stream>>>(Qb, Kb, Vb);

        transpose_w<<<dim3(32, 32), 256, 0, stream>>>(w_proj, 2048, wT);
        gemm_k<<<dim3(16, 32), 256, 0, stream>>>(Qb, wT, 2048, 1, 0,
                                                 out, nullptr, nullptr, nullptr);
    } else {
        // fallback (ws >= 58.7 MB), R5-proven sequence
        u16* wT = (u16*)d_ws;
        u16* Qb = wT + (size_t)2048 * 2048;
        u16* Kb = Qb + SEG;
        u16* Vb = Kb + SEG;

        transpose_w<<<dim3(32, 32), 256, 0, stream>>>(w_qkv + 0, 6144, wT);
        gemm_k<<<dim3(16, 32), 256, 0, stream>>>(x, wT, 2048, 0, 1,
                                                 nullptr, Qb, nullptr, nullptr);
        transpose_w<<<dim3(32, 32), 256, 0, stream>>>(w_qkv + 2048, 6144, wT);
        gemm_k<<<dim3(16, 32), 256, 0, stream>>>(x, wT, 2048, 0, 1,
                                                 nullptr, Kb, nullptr, nullptr);
        transpose_w<<<dim3(32, 32), 256, 0, stream>>>(w_qkv + 4096, 6144, wT);
        gemm_k<<<dim3(16, 32), 256, 0, stream>>>(x, wT, 2048, 0, 2,
                                                 nullptr, nullptr, nullptr, Vb);

        attn_kernel<<<dim3(16, 16, 4), 256, 0, stream>>>(Qb, Kb, Vb);

        transpose_w<<<dim3(32, 32), 256, 0, stream>>>(w_proj, 2048, wT);
        gemm_k<<<dim3(16, 32), 256, 0, stream>>>(Qb, wT, 2048, 3, 0,
                                                 out, nullptr, nullptr, nullptr);
    }
}

// Round 8
// 476.869 us; speedup vs baseline: 1.2279x; 1.2279x over previous
//
#include <hip/hip_runtime.h>
#include <cstdint>
#include <cstddef>

// Causal self-attention. fp32 in / fp32 out. bf16 MFMA compute, fp32 accum.
// B=4 T=1024 C=2048 H=16 Dh=128.
//
// R8 attention: S^T = K.Q^T scalar-softmax (R7) + LDS staging via
// global_load_lds (R5/m97) + XOR-swizzle (chunk ^= row&7, applied on the
// per-lane GLOBAL source address since the LDS dst must be lane-contiguous)
// to kill the unpadded-row bank conflicts. Diagonal tt-skip. 2 barriers/iter.
// R7 lesson: direct-global MFMA operands serialize on VGPR-bound loads
// (~16K cyc/iter); async16's VGPR-free deep queue is the fix.

typedef __attribute__((ext_vector_type(8))) __bf16 bf16x8;
typedef __attribute__((ext_vector_type(4))) float f32x4;
typedef unsigned short u16;

#define NEG_BIG (-1.0e30f)

__device__ __forceinline__ u16 f2bf(float f) {
    union { float f; uint32_t u; } v; v.f = f;
    uint32_t r = v.u + 0x7FFFu + ((v.u >> 16) & 1u);   // RNE
    return (u16)(r >> 16);
}

__device__ __forceinline__ uint32_t pack2(float a, float b) {
    return (uint32_t)f2bf(a) | ((uint32_t)f2bf(b) << 16);
}

__device__ __forceinline__ f32x4 mfma16(bf16x8 a, bf16x8 b, f32x4 c) {
    return __builtin_amdgcn_mfma_f32_16x16x32_bf16(a, b, c, 0, 0, 0);
}

// async global->LDS, 16B/lane; LDS dst = wave-uniform base (+lane*16 by HW)
__device__ __forceinline__ void async16(const u16* g, u16* l) {
    __builtin_amdgcn_global_load_lds(
        (const __attribute__((address_space(1))) void*)g,
        (__attribute__((address_space(3))) void*)l, 16, 0, 0);
}

// ---------------------------------------------------------------------------
__global__ __launch_bounds__(256) void cvt_bf16(
    const float* __restrict__ x, u16* __restrict__ xb) {
    size_t i = ((size_t)blockIdx.x * 256 + threadIdx.x) * 8;
    float4 u = *(const float4*)(x + i);
    float4 v = *(const float4*)(x + i + 4);
    uint4 p;
    p.x = pack2(u.x, u.y); p.y = pack2(u.z, u.w);
    p.z = pack2(v.x, v.y); p.w = pack2(v.z, v.w);
    *(uint4*)(xb + i) = p;
}

// ---------------------------------------------------------------------------
__global__ __launch_bounds__(256) void transpose_w(
    const float* __restrict__ W, int ldW, u16* __restrict__ WT) {
    __shared__ u16 tile[64][68];
    const int n0 = blockIdx.x * 64, k0 = blockIdx.y * 64;
    const int t = threadIdx.x;
    for (int i = t; i < 4096; i += 256) {
        int r = i >> 6, c = i & 63;
        tile[r][c] = f2bf(W[(size_t)(k0 + r) * ldW + n0 + c]);
    }
    __syncthreads();
    for (int i = t; i < 4096; i += 256) {
        int r = i >> 6, c = i & 63;
        WT[(size_t)(n0 + r) * 2048 + k0 + c] = tile[c][r];
    }
}

// ---------------------------------------------------------------------------
// GEMM (unchanged from R6): C[M,N] = A[M,2048] @ Bt[N,2048].
// ---------------------------------------------------------------------------
__global__ __launch_bounds__(256) void gemm_k(
    const void* __restrict__ Av, const u16* __restrict__ Bt,
    int N, int amode, int omode,
    float* __restrict__ outf, u16* __restrict__ Qo, u16* __restrict__ Ko,
    u16* __restrict__ Vt) {
    const int K = 2048;
    __shared__ u16 As[128][32];
    __shared__ u16 Bs[128][32];

    const float* A32 = (const float*)Av;
    const u16*   A16 = (const u16*)Av;

    const int m0 = blockIdx.y * 128, n0 = blockIdx.x * 128;
    const int t = threadIdx.x;
    const int w = t >> 6, lane = t & 63;
    const int col = lane & 15, quad = lane >> 4;
    const int wrow = (w >> 1) * 64, wcol = (w & 1) * 64;

    f32x4 acc[4][4];
    #pragma unroll
    for (int i = 0; i < 4; ++i)
        #pragma unroll
        for (int j = 0; j < 4; ++j)
            acc[i][j] = (f32x4){0.f, 0.f, 0.f, 0.f};

    u16* as_flat = &As[0][0];
    u16* bs_flat = &Bs[0][0];
    const int c1 = (w << 6) | lane;
    const int c2 = c1 + 256;

    for (int k0 = 0; k0 < K; k0 += 32) {
        {
            const u16* g1 = Bt + (size_t)(n0 + (c1 >> 2)) * K + k0 + ((c1 & 3) << 3);
            async16(g1, bs_flat + (size_t)w * 512);
            const u16* g2 = Bt + (size_t)(n0 + (c2 >> 2)) * K + k0 + ((c2 & 3) << 3);
            async16(g2, bs_flat + 2048 + (size_t)w * 512);
        }
        if (amode == 2) {
            const u16* g1 = A16 + (size_t)(m0 + (c1 >> 2)) * K + k0 + ((c1 & 3) << 3);
            async16(g1, as_flat + (size_t)w * 512);
            const u16* g2 = A16 + (size_t)(m0 + (c2 >> 2)) * K + k0 + ((c2 & 3) << 3);
            async16(g2, as_flat + 2048 + (size_t)w * 512);
        } else if (amode == 1) {
            #pragma unroll
            for (int cc = 0; cc < 2; ++cc) {
                int c = cc ? c2 : c1;
                int r = c >> 2, ko = (c & 3) << 3;
                int kg = k0 + ko, h = kg >> 7, d = kg & 127;
                int m = m0 + r, b = m >> 10, tt = m & 1023;
                const u16* g = A16 + (((size_t)(b * 16 + h)) * 1024 + tt) * 128 + d;
                async16(g, as_flat + (size_t)(cc ? 2048 : 0) + (size_t)w * 512);
            }
        } else if (amode == 0) {
            #pragma unroll
            for (int c = t; c < 512; c += 256) {
                int r = c >> 2, ko = (c & 3) * 8;
                size_t off = (size_t)(m0 + r) * K + k0 + ko;
                float4 u = *(const float4*)(A32 + off);
                float4 v = *(const float4*)(A32 + off + 4);
                uint4 p;
                p.x = pack2(u.x, u.y); p.y = pack2(u.z, u.w);
                p.z = pack2(v.x, v.y); p.w = pack2(v.z, v.w);
                *(uint4*)&As[r][ko] = p;
            }
        } else {
            #pragma unroll
            for (int c = t; c < 512; c += 256) {
                int r = c >> 2, ko = (c & 3) * 8;
                int kg = k0 + ko, h = kg >> 7, d = kg & 127;
                int m = m0 + r, b = m >> 10, tt = m & 1023;
                *(uint4*)&As[r][ko] =
                    *(const uint4*)(A16 + (((size_t)(b * 16 + h)) * 1024 + tt) * 128 + d);
            }
        }
        __syncthreads();

        bf16x8 afr[4], bfr[4];
        #pragma unroll
        for (int i = 0; i < 4; ++i)
            afr[i] = *(const bf16x8*)&As[wrow + i * 16 + col][quad * 8];
        #pragma unroll
        for (int i = 0; i < 4; ++i)
            bfr[i] = *(const bf16x8*)&Bs[wcol + i * 16 + col][quad * 8];

        #pragma unroll
        for (int mt = 0; mt < 4; ++mt)
            #pragma unroll
            for (int nt = 0; nt < 4; ++nt)
                acc[mt][nt] = mfma16(afr[mt], bfr[nt], acc[mt][nt]);
        __syncthreads();
    }

    #pragma unroll
    for (int mt = 0; mt < 4; ++mt) {
        #pragma unroll
        for (int nt = 0; nt < 4; ++nt) {
            #pragma unroll
            for (int r = 0; r < 4; ++r) {
                int gm = m0 + wrow + mt * 16 + quad * 4 + r;
                int gn = n0 + wcol + nt * 16 + col;
                if (omode == 0) {
                    outf[(size_t)gm * N + gn] = acc[mt][nt][r];
                } else {
                    u16 bv = f2bf(acc[mt][nt][r]);
                    int b = gm >> 10, tq = gm & 1023;
                    if (omode == 3) {
                        int which = gn >> 11, rem = gn & 2047;
                        int h = rem >> 7, d = rem & 127;
                        size_t bh = (size_t)b * 16 + h;
                        if (which == 0)      Qo[(bh * 1024 + tq) * 128 + d] = bv;
                        else if (which == 1) Ko[(bh * 1024 + tq) * 128 + d] = bv;
                        else                 Vt[(bh * 128 + d) * 1024 + tq] = bv;
                    } else {
                        int h = gn >> 7, d = gn & 127;
                        size_t bh = (size_t)b * 16 + h;
                        if (omode == 1) Qo[(bh * 1024 + tq) * 128 + d] = bv;
                        else            Vt[(bh * 128 + d) * 1024 + tq] = bv;
                    }
                }
            }
        }
    }
}

// ---------------------------------------------------------------------------
// Flash attention R8. Grid (T/64, H, B), 256 threads = 4 waves, 16 q/wave.
// K tile [64][128] and V^T tile [128][64] staged via async16 with XOR-swizzle
// (LDS chunk (r,c) holds global chunk c^(r&7)); frag reads apply the same XOR
// -> bank pattern equals the proven GEMM LDS pattern. S^T formulation:
// lane holds S^T[t=tt*16+quad*4+r][q=col]; m/l/alpha scalar, 2-stage shuffle.
// Ps wave-private (barrier-free). O overwrites Q in place.
// ---------------------------------------------------------------------------
__global__ __launch_bounds__(256) void attn_kernel(
    u16* __restrict__ Q, const u16* __restrict__ K,
    const u16* __restrict__ VT) {
    __shared__ u16 Ks[64 * 128];     // swizzled, unpadded (async16 dst)
    __shared__ u16 Vs[128 * 64];     // swizzled, unpadded
    __shared__ u16 Ps[4][16][68];    // wave-private, padded (normal ds_write)

    const int qb = (int)(gridDim.x - 1) - (int)blockIdx.x;   // heavy first
    const int h = blockIdx.y, b = blockIdx.z;
    const int t = threadIdx.x;
    const int w = t >> 6, lane = t & 63;
    const int col = lane & 15, quad = lane >> 4;
    const int sw = col & 7;                       // read-side swizzle key
    const size_t bh = (size_t)b * 16 + h;
    u16* Qb = Q + bh * (1024 * 128);
    const u16* Kb = K + bh * (1024 * 128);
    const u16* Vb = VT + bh * (128 * 1024);
    const int q_lane = qb * 64 + w * 16 + col;

    // Q fragment, B-operand: lane holds Q[q=col][dh=kq*32+quad*8+j]
    bf16x8 qf[4];
    {
        const u16* qp = Qb + (size_t)q_lane * 128 + quad * 8;
        #pragma unroll
        for (int kq = 0; kq < 4; ++kq)
            qf[kq] = *(const bf16x8*)(qp + kq * 32);
    }

    f32x4 o[8];
    #pragma unroll
    for (int i = 0; i < 8; ++i) o[i] = (f32x4){0.f, 0.f, 0.f, 0.f};
    float m = NEG_BIG, l = 0.f;
    const float scale = 0.08838834764831845f;  // 1/sqrt(128)

    for (int kt = 0; kt <= qb; ++kt) {
        const u16* Kt = Kb + (size_t)kt * (64 * 128);

        // ---- stage K (64x128) + V^T (128x64) via swizzled async16 ----
        #pragma unroll
        for (int i = 0; i < 4; ++i) {
            int s = i * 256 + w * 64 + lane;          // chunk slot incl. lane
            int kr = s >> 4, kc = s & 15;             // K: 16 chunks/row
            async16(Kt + (size_t)kr * 128 + ((kc ^ (kr & 7)) << 3),
                    Ks + (size_t)(i * 256 + w * 64) * 8);
            int vr = s >> 3, vc = s & 7;              // V: 8 chunks/row
            async16(Vb + (size_t)vr * 1024 + kt * 64 + ((vc ^ (vr & 7)) << 3),
                    Vs + (size_t)(i * 256 + w * 64) * 8);
        }
        __syncthreads();

        // ---- S^T = K.Q^T ----
        const bool need_mask = (kt == qb);
        const int ttmax = need_mask ? w : 3;          // skip fully-masked strips
        f32x4 s[4];
        #pragma unroll
        for (int tt = 0; tt < 4; ++tt) {
            if (tt > ttmax) { s[tt] = (f32x4){NEG_BIG, NEG_BIG, NEG_BIG, NEG_BIG}; continue; }
            const u16* kbase = Ks + (size_t)(tt * 16 + col) * 128;
            f32x4 a = (f32x4){0.f, 0.f, 0.f, 0.f};
            #pragma unroll
            for (int kq = 0; kq < 4; ++kq)
                a = mfma16(*(const bf16x8*)(kbase + (((kq * 4 + quad) ^ sw) << 3)),
                           qf[kq], a);
            s[tt] = a;
        }

        // ---- scale + mask + max ----
        float rmax = NEG_BIG;
        #pragma unroll
        for (int tt = 0; tt < 4; ++tt) {
            if (tt > ttmax) continue;
            #pragma unroll
            for (int r = 0; r < 4; ++r) {
                float v = s[tt][r] * scale;
                int tg = kt * 64 + tt * 16 + quad * 4 + r;
                if (need_mask && tg > q_lane) v = NEG_BIG;
                s[tt][r] = v;
                rmax = fmaxf(rmax, v);
            }
        }
        rmax = fmaxf(rmax, __shfl_xor(rmax, 16, 64));
        rmax = fmaxf(rmax, __shfl_xor(rmax, 32, 64));

        float mnew = fmaxf(m, rmax);
        float alpha = __expf(m - mnew);
        m = mnew;

        // ---- P = exp(S^T - m) -> Ps[w][q][t] ----
        float rsum = 0.f;
        #pragma unroll
        for (int tt = 0; tt < 4; ++tt) {
            uint32_t* dst = (uint32_t*)&Ps[w][col][tt * 16 + quad * 4];
            if (tt > ttmax) { dst[0] = 0u; dst[1] = 0u; continue; }
            float p0 = __expf(s[tt][0] - mnew);
            float p1 = __expf(s[tt][1] - mnew);
            float p2 = __expf(s[tt][2] - mnew);
            float p3 = __expf(s[tt][3] - mnew);
            rsum += (p0 + p1) + (p2 + p3);
            dst[0] = pack2(p0, p1);
            dst[1] = pack2(p2, p3);
        }
        rsum += __shfl_xor(rsum, 16, 64);
        rsum += __shfl_xor(rsum, 32, 64);
        l = l * alpha + rsum;

        #pragma unroll
        for (int dt = 0; dt < 8; ++dt)
            #pragma unroll
            for (int r = 0; r < 4; ++r) o[dt][r] *= alpha;

        // ---- O^T += V^T.P^T ----
        #pragma unroll
        for (int ks = 0; ks < 2; ++ks) {
            bf16x8 pf = *(const bf16x8*)&Ps[w][col][ks * 32 + quad * 8];
            #pragma unroll
            for (int dt = 0; dt < 8; ++dt) {
                const u16* vbase = Vs + (size_t)(dt * 16 + col) * 64;
                o[dt] = mfma16(*(const bf16x8*)(vbase + (((ks * 4 + quad) ^ sw) << 3)),
                               pf, o[dt]);
            }
        }
        __syncthreads();   // all waves done reading before next overwrite
    }

    // epilogue: lane holds O^T[d=dt*16+quad*4+r][q=col]; 8B packed stores
    float inv = 1.0f / l;
    #pragma unroll
    for (int dt = 0; dt < 8; ++dt) {
        uint2 p;
        p.x = pack2(o[dt][0] * inv, o[dt][1] * inv);
        p.y = pack2(o[dt][2] * inv, o[dt][3] * inv);
        *(uint2*)&Qb[(size_t)q_lane * 128 + dt * 16 + quad * 4] = p;
    }
}

// ---------------------------------------------------------------------------
extern "C" void kernel_launch(void* const* d_in, const int* in_sizes, int n_in,
                              void* d_out, int out_size, void* d_ws, size_t ws_size,
                              hipStream_t stream) {
    const float* x      = (const float*)d_in[0];   // [4096, 2048]
    const float* w_qkv  = (const float*)d_in[1];   // [2048, 6144]
    const float* w_proj = (const float*)d_in[2];   // [2048, 2048]
    float* out = (float*)d_out;                    // [4096, 2048]

    const size_t SEG = (size_t)4 * 16 * 1024 * 128;      // 8,388,608 elems
    const size_t NEED_FAST = ((size_t)6144 * 2048 + SEG * 4) * 2;  // 92.3 MB

    if (ws_size >= NEED_FAST + (1u << 20)) {
        u16* wT = (u16*)d_ws;                 // 6144*2048, reused for proj
        u16* xb = wT + (size_t)6144 * 2048;
        u16* Qb = xb + SEG;
        u16* Kb = Qb + SEG;
        u16* Vb = Kb + SEG;

        cvt_bf16<<<4096, 256, 0, stream>>>(x, xb);
        transpose_w<<<dim3(96, 32), 256, 0, stream>>>(w_qkv, 6144, wT);

        gemm_k<<<dim3(48, 32), 256, 0, stream>>>(xb, wT, 6144, 2, 3,
                                                 nullptr, Qb, Kb, Vb);

        attn_kernel<<<dim3(16, 16, 4), 256, 0, stream>>>(Qb, Kb, Vb);

        transpose_w<<<dim3(32, 32), 256, 0, stream>>>(w_proj, 2048, wT);
        gemm_k<<<dim3(16, 32), 256, 0, stream>>>(Qb, wT, 2048, 1, 0,
                                                 out, nullptr, nullptr, nullptr);
    } else {
        // fallback (ws >= 58.7 MB), R5-proven sequence
        u16* wT = (u16*)d_ws;
        u16* Qb = wT + (size_t)2048 * 2048;
        u16* Kb = Qb + SEG;
        u16* Vb = Kb + SEG;

        transpose_w<<<dim3(32, 32), 256, 0, stream>>>(w_qkv + 0, 6144, wT);
        gemm_k<<<dim3(16, 32), 256, 0, stream>>>(x, wT, 2048, 0, 1,
                                                 nullptr, Qb, nullptr, nullptr);
        transpose_w<<<dim3(32, 32), 256, 0, stream>>>(w_qkv + 2048, 6144, wT);
        gemm_k<<<dim3(16, 32), 256, 0, stream>>>(x, wT, 2048, 0, 1,
                                                 nullptr, Kb, nullptr, nullptr);
        transpose_w<<<dim3(32, 32), 256, 0, stream>>>(w_qkv + 4096, 6144, wT);
        gemm_k<<<dim3(16, 32), 256, 0, stream>>>(x, wT, 2048, 0, 2,
                                                 nullptr, nullptr, nullptr, Vb);

        attn_kernel<<<dim3(16, 16, 4), 256, 0, stream>>>(Qb, Kb, Vb);

        transpose_w<<<dim3(32, 32), 256, 0, stream>>>(w_proj, 2048, wT);
        gemm_k<<<dim3(16, 32), 256, 0, stream>>>(Qb, wT, 2048, 3, 0,
                                                 out, nullptr, nullptr, nullptr);
    }
}